// Round 1
// baseline (111.610 us; speedup 1.0000x reference)
//
#include <hip/hip_runtime.h>

#define BB 4
#define TQ 512
#define TK 512
#define DQ 512
#define UU 256
#define CSC 2.8853900817779268f   // 2*log2(e): Eq=2^(CSC*q), Ek=2^(CSC*k), e^{2y}=Eq*Ek
#define L2E 1.4426950408889634f
#define RQ 4

typedef unsigned short u16;
typedef unsigned int u32;
typedef short bf16x8 __attribute__((ext_vector_type(8)));
typedef float f32x4 __attribute__((ext_vector_type(4)));
typedef float f32x2 __attribute__((ext_vector_type(2)));

__device__ __forceinline__ float fexp2(float x) { return __builtin_amdgcn_exp2f(x); }
__device__ __forceinline__ float frcp(float x)  { return __builtin_amdgcn_rcpf(x); }
__device__ __forceinline__ u32 pkhi(u32 a, u32 b) { return (b & 0xffff0000u) | (a >> 16); }

// wsplit: transpose+split W1/W2 (fp32 [512k][256n]) -> Wh_t/Wl_t (u16 [256n][512k]).
__global__ __launch_bounds__(256) void wsplit(
    const float* __restrict__ W1, const float* __restrict__ W2,
    u16* __restrict__ W1h, u16* __restrict__ W1l,
    u16* __restrict__ W2h, u16* __restrict__ W2l)
{
    __shared__ float tile[32][33];
    const int blk = blockIdx.x, t = threadIdx.x;
    const float* W = (blk >> 7) ? W2 : W1;
    u16* oh = (blk >> 7) ? W2h : W1h;
    u16* ol = (blk >> 7) ? W2l : W1l;
    const int tl = blk & 127;
    const int k0 = (tl >> 3) * 32, n0 = (tl & 7) * 32;
    const int kl = t >> 5, nl = t & 31;
    #pragma unroll
    for (int r = 0; r < 4; r++)
        tile[kl + 8 * r][nl] = W[(size_t)(k0 + kl + 8 * r) * UU + n0 + nl];
    __syncthreads();
    const int nr = t >> 5, kc = t & 31;
    #pragma unroll
    for (int r = 0; r < 4; r++) {
        const float v = tile[kc][nr + 8 * r];
        const u32 x = __float_as_uint(v);
        const u16 h = (u16)(x >> 16);
        const u16 l = (u16)(__float_as_uint(v - __uint_as_float(x & 0xffff0000u)) >> 16);
        oh[(size_t)(n0 + nr + 8 * r) * DQ + k0 + kc] = h;
        ol[(size_t)(n0 + nr + 8 * r) * DQ + k0 + kc] = l;
    }
}

// proj3: C = A@W, split-bf16 MFMA (truncation split, 3 terms), exp2(CSC*acc) epilogue.
// Tile 32m x 64n, K chunks of 32. A: global->split->LDS, double-buffered, 1 barrier/iter.
// W: pre-split planes, per-lane b128 global loads, register double-buffer issued AFTER
// the barrier so they drain at barrier(i+1). Grid (64,4,2) = 512 blocks, 4 waves each.
// z=0: Eq ROW-PAIR interleaved [b][q/2][u][2] (feeds packed-f32 attn math directly).
// z=1: Ek interleaved [b][u/4][j][4] via LDS bounce.
__global__ __launch_bounds__(256) void proj3(
    const float* __restrict__ Aq, const float* __restrict__ Av,
    const u16* __restrict__ W1h, const u16* __restrict__ W1l,
    const u16* __restrict__ W2h, const u16* __restrict__ W2l,
    float* __restrict__ Eq, float* __restrict__ Ek)
{
    __shared__ __align__(16) char raw[10240];   // 2 x 5120: Ah [32][40] + Al [32][40] u16
    float* fin = (float*)raw;                   // [32][68] f32, aliases after final barrier

    const int z = blockIdx.z;
    const float* A = z ? Av : Aq;
    const u16* Wh = z ? W2h : W1h;
    const u16* Wl = z ? W2l : W1l;

    const int t = threadIdx.x;
    const int m0 = blockIdx.x * 32, n0 = blockIdx.y * 64;
    const int wave = t >> 6, ln = t & 15, qd = (t & 63) >> 4;
    const int arow = t >> 3, ak4 = (t & 7) * 4;        // A staging: 4 fp32/thread
    const int ncol = n0 + wave * 16 + ln;
    const u16* whp = Wh + (size_t)ncol * DQ + qd * 8;
    const u16* wlp = Wl + (size_t)ncol * DQ + qd * 8;

    f32x4 acc[2] = {};

    float4 a4 = *(const float4*)&A[(size_t)(m0 + arow) * DQ + ak4];
    bf16x8 whc = *(const bf16x8*)&whp[0];
    bf16x8 wlc = *(const bf16x8*)&wlp[0];

    for (int i = 0; i < DQ / 32; i++) {
        char* buf = raw + (i & 1) * 5120;
        u16* Ah_s = (u16*)buf;
        u16* Al_s = (u16*)(buf + 2560);
        {   // A split -> bf16 hi/lo planes
            const float f[4] = {a4.x, a4.y, a4.z, a4.w};
            u32 x[4], lx[4];
            #pragma unroll
            for (int e = 0; e < 4; e++) {
                x[e]  = __float_as_uint(f[e]);
                lx[e] = __float_as_uint(f[e] - __uint_as_float(x[e] & 0xffff0000u));
            }
            uint2 hw, lw;
            hw.x = pkhi(x[0], x[1]);  hw.y = pkhi(x[2], x[3]);
            lw.x = pkhi(lx[0], lx[1]); lw.y = pkhi(lx[2], lx[3]);
            *(uint2*)&Ah_s[arow * 40 + ak4] = hw;
            *(uint2*)&Al_s[arow * 40 + ak4] = lw;
        }
        if (i + 1 < DQ / 32)
            a4 = *(const float4*)&A[(size_t)(m0 + arow) * DQ + (i + 1) * 32 + ak4];
        __syncthreads();

        bf16x8 whn, wln;
        if (i + 1 < DQ / 32) {  // W prefetch AFTER barrier -> drains at barrier(i+1)
            whn = *(const bf16x8*)&whp[(i + 1) * 32];
            wln = *(const bf16x8*)&wlp[(i + 1) * 32];
        }

        bf16x8 ah[2], al[2];
        #pragma unroll
        for (int ii = 0; ii < 2; ii++) {
            const int ar = (ii * 16 + ln) * 40 + qd * 8;
            ah[ii] = *(const bf16x8*)&Ah_s[ar];
            al[ii] = *(const bf16x8*)&Al_s[ar];
        }
        #pragma unroll
        for (int ii = 0; ii < 2; ii++) {
            acc[ii] = __builtin_amdgcn_mfma_f32_16x16x32_bf16(ah[ii], whc, acc[ii], 0, 0, 0);
            acc[ii] = __builtin_amdgcn_mfma_f32_16x16x32_bf16(ah[ii], wlc, acc[ii], 0, 0, 0);
            acc[ii] = __builtin_amdgcn_mfma_f32_16x16x32_bf16(al[ii], whc, acc[ii], 0, 0, 0);
        }
        whc = whn; wlc = wln;
    }

    if (z == 0) {
        // Row-pair interleaved Eq: Eq[((m>>1)*UU + ncol)*2 + (m&1)].
        // Each thread owns rows qd*4..qd*4+3 -> two aligned pairs; float2 stores,
        // lanes (ln=ncol consecutive) -> contiguous 8B x 16 = 128B segments.
        #pragma unroll
        for (int ii = 0; ii < 2; ii++) {
            #pragma unroll
            for (int r = 0; r < 4; r += 2) {
                const int m = m0 + ii * 16 + qd * 4 + r;   // even
                float2 v;
                v.x = fexp2(CSC * acc[ii][r]);
                v.y = fexp2(CSC * acc[ii][r + 1]);
                *(float2*)&Eq[((size_t)(m >> 1) * UU + ncol) * 2] = v;
            }
        }
    } else {
        __syncthreads();
        #pragma unroll
        for (int ii = 0; ii < 2; ii++) {
            #pragma unroll
            for (int r = 0; r < 4; r++) {
                const int ml = ii * 16 + qd * 4 + r;
                const int nl = wave * 16 + ln;
                fin[ml * 68 + nl] = fexp2(CSC * acc[ii][r]);
            }
        }
        __syncthreads();
        const int b = m0 >> 9, j0 = m0 & 511;
        #pragma unroll
        for (int p = 0; p < 2; p++) {
            const int idx = p * 256 + t;
            const int jl = idx & 31, u4 = idx >> 5;
            const float4 v = *(const float4*)&fin[jl * 68 + u4 * 4];
            ((float4*)Ek)[(size_t)(b * (UU / 4) + (n0 >> 2) + u4) * TK + j0 + jl] = v;
        }
    }
}

// attn+softmax: e^{2y} = Eq*Ek; shifted_score = -2*sum_u scale_u/(1+Eq*Ek).
// 4-way rcp batching (exact algebra, overflow-safe: d<=~1.1e9 so d0*d1*d2*d3<=1.5e36):
//   num = (s0*d1+s1*d0)*d2*d3 + (s2*d3+s3*d2)*d0*d1 ; den = (d0*d1)*(d2*d3)
// Packed f32 (v_pk_fma_f32) across q-ROW-PAIRS: Eq is [b][q/2][u][2] interleaved, so
// one float4 load = two adjacent row-pair float2's -> no v_mov packing. k/scale
// broadcast to both halves (op_sel). Only rcp is scalar (2 per 4u per row-pair).
// k prefetch: NAMED float4 regs, statically indexed (R10's dynamically-indexed kbuf[4]
// got LDS-promoted: 33KB alloca + 1.9e7 bank conflicts -- never index these).
__global__ __launch_bounds__(512) void attn_softmax(
    const float* __restrict__ Eq,    // [BB, TQ/2, UU, 2] row-pair interleaved
    const float* __restrict__ Ek,    // [BB, UU/4, TK] of float4 (interleaved u)
    const float* __restrict__ scale, // [UU]
    float* __restrict__ out)         // [BB, TQ, TK]
{
    __shared__ float redbuf[RQ][8];
    const int t  = threadIdx.x;
    const int b  = blockIdx.x >> 7;            // 128 blocks per b
    const int q0 = (blockIdx.x & 127) * RQ;
    const float*  qrow = Eq + (size_t)(b * TQ + q0) * UU;   // wave-uniform pair base
    const float4* kb4  = (const float4*)Ek + (size_t)b * (UU / 4) * TK + t;

    f32x2 acc2[RQ / 2] = {};

    auto body = [&](const float4& kv, int g) {
        const float4 sc4 = *(const float4*)&scale[4 * g];    // wave-uniform
        const float s0 = sc4.x, s1 = sc4.y, s2 = sc4.z, s3 = sc4.w;
        const float k0 = kv.x, k1 = kv.y, k2 = kv.z, k3 = kv.w;
        #pragma unroll
        for (int h = 0; h < RQ / 2; h++) {
            const float4 qa = *(const float4*)&qrow[(size_t)h * (2 * UU) + 8 * g];
            const float4 qb = *(const float4*)&qrow[(size_t)h * (2 * UU) + 8 * g + 4];
            const f32x2 q0v = {qa.x, qa.y}, q1v = {qa.z, qa.w};
            const f32x2 q2v = {qb.x, qb.y}, q3v = {qb.z, qb.w};
            const f32x2 d0 = q0v * k0 + 1.0f;
            const f32x2 d1 = q1v * k1 + 1.0f;
            const f32x2 d2 = q2v * k2 + 1.0f;
            const f32x2 d3 = q3v * k3 + 1.0f;
            const f32x2 p01 = d0 * d1, p23 = d2 * d3;
            const f32x2 n01 = s0 * d1 + s1 * d0;
            const f32x2 n23 = s2 * d3 + s3 * d2;
            const f32x2 num = n01 * p23 + n23 * p01;
            const f32x2 den = p01 * p23;
            const f32x2 rcp2 = {frcp(den.x), frcp(den.y)};
            acc2[h] += num * rcp2;
        }
    };

    float4 c0 = kb4[0];
    float4 c1 = kb4[(size_t)TK];
    float4 c2 = kb4[(size_t)2 * TK];
    float4 c3 = kb4[(size_t)3 * TK];
    for (int g = 0; g < UU / 4; g += 4) {
        float4 n0v, n1v, n2v, n3v;
        if (g + 4 < UU / 4) {
            n0v = kb4[(size_t)(g + 4) * TK];
            n1v = kb4[(size_t)(g + 5) * TK];
            n2v = kb4[(size_t)(g + 6) * TK];
            n3v = kb4[(size_t)(g + 7) * TK];
        }
        body(c0, g); body(c1, g + 1); body(c2, g + 2); body(c3, g + 3);
        c0 = n0v; c1 = n1v; c2 = n2v; c3 = n3v;
    }

    float accs[RQ];
    #pragma unroll
    for (int r = 0; r < RQ; r++)
        accs[r] = ((r & 1) ? acc2[r >> 1].y : acc2[r >> 1].x) * -2.0f;

    const int wave = t >> 6, lane = t & 63;
    float m[RQ], p[RQ];

    // row max over 512 threads
    #pragma unroll
    for (int r = 0; r < RQ; r++) {
        float v = accs[r];
        #pragma unroll
        for (int o = 32; o > 0; o >>= 1) v = fmaxf(v, __shfl_xor(v, o));
        if (lane == 0) redbuf[r][wave] = v;
    }
    __syncthreads();
    #pragma unroll
    for (int r = 0; r < RQ; r++) {
        float v = redbuf[r][0];
        #pragma unroll
        for (int w = 1; w < 8; w++) v = fmaxf(v, redbuf[r][w]);
        m[r] = v;
    }
    __syncthreads();

    // exp and row sum
    #pragma unroll
    for (int r = 0; r < RQ; r++) {
        p[r] = fexp2(L2E * (accs[r] - m[r]));
        float v = p[r];
        #pragma unroll
        for (int o = 32; o > 0; o >>= 1) v += __shfl_xor(v, o);
        if (lane == 0) redbuf[r][wave] = v;
    }
    __syncthreads();
    #pragma unroll
    for (int r = 0; r < RQ; r++) {
        float v = 0.0f;
        #pragma unroll
        for (int w = 0; w < 8; w++) v += redbuf[r][w];
        const float rinv = frcp(v);
        out[(size_t)(b * TQ + q0 + r) * TK + t] = p[r] * rinv;
    }
}

extern "C" void kernel_launch(void* const* d_in, const int* in_sizes, int n_in,
                              void* d_out, int out_size, void* d_ws, size_t ws_size,
                              hipStream_t stream) {
    const float* query = (const float*)d_in[0];
    const float* value = (const float*)d_in[1];
    const float* W1    = (const float*)d_in[2];
    const float* W2    = (const float*)d_in[3];
    const float* scale = (const float*)d_in[4];
    float* out = (float*)d_out;

    float* Eq = (float*)d_ws;                     // [BB*TQ/2, UU, 2]  2 MB
    float* Ek = Eq + (size_t)BB * TQ * UU;        // [BB,UU/4,TK] f4   2 MB
    char* wbase = (char*)d_ws + 4 * 1048576;      // W planes: 4 x 256 KB
    u16* W1h = (u16*)(wbase);
    u16* W1l = (u16*)(wbase + 262144);
    u16* W2h = (u16*)(wbase + 524288);
    u16* W2l = (u16*)(wbase + 786432);
    (void)ws_size;  // needs 5 MB; harness provides 256 MB (verified R11/R12 profile)

    wsplit<<<256, 256, 0, stream>>>(W1, W2, W1h, W1l, W2h, W2l);
    proj3<<<dim3(64, 4, 2), 256, 0, stream>>>(query, value, W1h, W1l, W2h, W2l, Eq, Ek);
    attn_softmax<<<dim3(BB * TQ / RQ), 512, 0, stream>>>(Eq, Ek, scale, out);
}

// Round 2
// 106.428 us; speedup vs baseline: 1.0487x; 1.0487x over previous
//
#include <hip/hip_runtime.h>

#define BB 4
#define TQ 512
#define TK 512
#define DQ 512
#define UU 256
#define CSC 2.8853900817779268f   // 2*log2(e): Eq=2^(CSC*q), Ek=2^(CSC*k), e^{2y}=Eq*Ek
#define L2E 1.4426950408889634f
#define RQ 4

typedef unsigned short u16;
typedef unsigned int u32;
typedef short bf16x8 __attribute__((ext_vector_type(8)));
typedef float f32x4 __attribute__((ext_vector_type(4)));

__device__ __forceinline__ float fexp2(float x) { return __builtin_amdgcn_exp2f(x); }
__device__ __forceinline__ float frcp(float x)  { return __builtin_amdgcn_rcpf(x); }
__device__ __forceinline__ u32 pkhi(u32 a, u32 b) { return (b & 0xffff0000u) | (a >> 16); }

// wsplit: transpose+split W1/W2 (fp32 [512k][256n]) -> Wh_t/Wl_t (u16 [256n][512k]).
__global__ __launch_bounds__(256) void wsplit(
    const float* __restrict__ W1, const float* __restrict__ W2,
    u16* __restrict__ W1h, u16* __restrict__ W1l,
    u16* __restrict__ W2h, u16* __restrict__ W2l)
{
    __shared__ float tile[32][33];
    const int blk = blockIdx.x, t = threadIdx.x;
    const float* W = (blk >> 7) ? W2 : W1;
    u16* oh = (blk >> 7) ? W2h : W1h;
    u16* ol = (blk >> 7) ? W2l : W1l;
    const int tl = blk & 127;
    const int k0 = (tl >> 3) * 32, n0 = (tl & 7) * 32;
    const int kl = t >> 5, nl = t & 31;
    #pragma unroll
    for (int r = 0; r < 4; r++)
        tile[kl + 8 * r][nl] = W[(size_t)(k0 + kl + 8 * r) * UU + n0 + nl];
    __syncthreads();
    const int nr = t >> 5, kc = t & 31;
    #pragma unroll
    for (int r = 0; r < 4; r++) {
        const float v = tile[kc][nr + 8 * r];
        const u32 x = __float_as_uint(v);
        const u16 h = (u16)(x >> 16);
        const u16 l = (u16)(__float_as_uint(v - __uint_as_float(x & 0xffff0000u)) >> 16);
        oh[(size_t)(n0 + nr + 8 * r) * DQ + k0 + kc] = h;
        ol[(size_t)(n0 + nr + 8 * r) * DQ + k0 + kc] = l;
    }
}

// proj3: C = A@W, split-bf16 MFMA (truncation split, 3 terms), exp2(CSC*acc) epilogue.
// Tile 32m x 64n, K chunks of 32. A: global->split->LDS, double-buffered, 1 barrier/iter.
// W: pre-split planes, per-lane b128 global loads, register double-buffer issued AFTER
// the barrier so they drain at barrier(i+1). Grid (64,4,2) = 512 blocks, 4 waves each.
// z=0: Eq[m][u] row-major.  z=1: Ek interleaved [b][u/4][j][4] via LDS bounce.
__global__ __launch_bounds__(256) void proj3(
    const float* __restrict__ Aq, const float* __restrict__ Av,
    const u16* __restrict__ W1h, const u16* __restrict__ W1l,
    const u16* __restrict__ W2h, const u16* __restrict__ W2l,
    float* __restrict__ Eq, float* __restrict__ Ek)
{
    __shared__ __align__(16) char raw[10240];   // 2 x 5120: Ah [32][40] + Al [32][40] u16
    float* fin = (float*)raw;                   // [32][68] f32, aliases after final barrier

    const int z = blockIdx.z;
    const float* A = z ? Av : Aq;
    const u16* Wh = z ? W2h : W1h;
    const u16* Wl = z ? W2l : W1l;

    const int t = threadIdx.x;
    const int m0 = blockIdx.x * 32, n0 = blockIdx.y * 64;
    const int wave = t >> 6, ln = t & 15, qd = (t & 63) >> 4;
    const int arow = t >> 3, ak4 = (t & 7) * 4;        // A staging: 4 fp32/thread
    const int ncol = n0 + wave * 16 + ln;
    const u16* whp = Wh + (size_t)ncol * DQ + qd * 8;
    const u16* wlp = Wl + (size_t)ncol * DQ + qd * 8;

    f32x4 acc[2] = {};

    float4 a4 = *(const float4*)&A[(size_t)(m0 + arow) * DQ + ak4];
    bf16x8 whc = *(const bf16x8*)&whp[0];
    bf16x8 wlc = *(const bf16x8*)&wlp[0];

    for (int i = 0; i < DQ / 32; i++) {
        char* buf = raw + (i & 1) * 5120;
        u16* Ah_s = (u16*)buf;
        u16* Al_s = (u16*)(buf + 2560);
        {   // A split -> bf16 hi/lo planes
            const float f[4] = {a4.x, a4.y, a4.z, a4.w};
            u32 x[4], lx[4];
            #pragma unroll
            for (int e = 0; e < 4; e++) {
                x[e]  = __float_as_uint(f[e]);
                lx[e] = __float_as_uint(f[e] - __uint_as_float(x[e] & 0xffff0000u));
            }
            uint2 hw, lw;
            hw.x = pkhi(x[0], x[1]);  hw.y = pkhi(x[2], x[3]);
            lw.x = pkhi(lx[0], lx[1]); lw.y = pkhi(lx[2], lx[3]);
            *(uint2*)&Ah_s[arow * 40 + ak4] = hw;
            *(uint2*)&Al_s[arow * 40 + ak4] = lw;
        }
        if (i + 1 < DQ / 32)
            a4 = *(const float4*)&A[(size_t)(m0 + arow) * DQ + (i + 1) * 32 + ak4];
        __syncthreads();

        bf16x8 whn, wln;
        if (i + 1 < DQ / 32) {  // W prefetch AFTER barrier -> drains at barrier(i+1)
            whn = *(const bf16x8*)&whp[(i + 1) * 32];
            wln = *(const bf16x8*)&wlp[(i + 1) * 32];
        }

        bf16x8 ah[2], al[2];
        #pragma unroll
        for (int ii = 0; ii < 2; ii++) {
            const int ar = (ii * 16 + ln) * 40 + qd * 8;
            ah[ii] = *(const bf16x8*)&Ah_s[ar];
            al[ii] = *(const bf16x8*)&Al_s[ar];
        }
        #pragma unroll
        for (int ii = 0; ii < 2; ii++) {
            acc[ii] = __builtin_amdgcn_mfma_f32_16x16x32_bf16(ah[ii], whc, acc[ii], 0, 0, 0);
            acc[ii] = __builtin_amdgcn_mfma_f32_16x16x32_bf16(ah[ii], wlc, acc[ii], 0, 0, 0);
            acc[ii] = __builtin_amdgcn_mfma_f32_16x16x32_bf16(al[ii], whc, acc[ii], 0, 0, 0);
        }
        whc = whn; wlc = wln;
    }

    if (z == 0) {
        #pragma unroll
        for (int ii = 0; ii < 2; ii++) {
            #pragma unroll
            for (int r = 0; r < 4; r++) {
                const int m = m0 + ii * 16 + qd * 4 + r;
                Eq[(size_t)m * UU + ncol] = fexp2(CSC * acc[ii][r]);
            }
        }
    } else {
        __syncthreads();
        #pragma unroll
        for (int ii = 0; ii < 2; ii++) {
            #pragma unroll
            for (int r = 0; r < 4; r++) {
                const int ml = ii * 16 + qd * 4 + r;
                const int nl = wave * 16 + ln;
                fin[ml * 68 + nl] = fexp2(CSC * acc[ii][r]);
            }
        }
        __syncthreads();
        const int b = m0 >> 9, j0 = m0 & 511;
        #pragma unroll
        for (int p = 0; p < 2; p++) {
            const int idx = p * 256 + t;
            const int jl = idx & 31, u4 = idx >> 5;
            const float4 v = *(const float4*)&fin[jl * 68 + u4 * 4];
            ((float4*)Ek)[(size_t)(b * (UU / 4) + (n0 >> 2) + u4) * TK + j0 + jl] = v;
        }
    }
}

// attn+softmax: e^{2y} = Eq*Ek; shifted_score = -2*sum_u scale_u/(1+Eq*Ek).
// 4-way rcp batching (exact algebra): for d_i = 1+Eq_i*Ek_i,
//   sum_i s_i/d_i = [ (s0*d1+s1*d0)*d2*d3 + (s2*d3+s3*d2)*d0*d1 ] / (d0*d1*d2*d3)
// Overflow-safe: d <= ~3e8 at the data's ~4.9-sigma tails -> den <= ~8e33 < FLT_MAX.
// 14 VALU + 1 rcp per 4u per row (was 12 VALU + 2 rcp): 36 vs 40 issue cyc (-10%).
// 8-way batching impossible in fp32 (den dynamic range ~2^240). NOTE (R1): f32x2/
// v_pk_fma_f32 is NOT a win on gfx950 -- CDNA4 packed f32 is not double-rate (157.3 TF
// spec = plain rate) and the compiler scalarizes ext_vector f32 anyway.
// k prefetch: NAMED float4 regs, statically indexed (R10's dynamically-indexed kbuf[4]
// got LDS-promoted: 33KB alloca + 1.9e7 bank conflicts -- never index these).
__global__ __launch_bounds__(512) void attn_softmax(
    const float* __restrict__ Eq,    // [BB, TQ, UU]
    const float* __restrict__ Ek,    // [BB, UU/4, TK] of float4 (interleaved u)
    const float* __restrict__ scale, // [UU]
    float* __restrict__ out)         // [BB, TQ, TK]
{
    __shared__ float redbuf[RQ][8];
    const int t  = threadIdx.x;
    const int b  = blockIdx.x >> 7;            // 128 blocks per b
    const int q0 = (blockIdx.x & 127) * RQ;
    const float*  qrow = Eq + (size_t)(b * TQ + q0) * UU;   // wave-uniform
    const float4* kb4  = (const float4*)Ek + (size_t)b * (UU / 4) * TK + t;

    float acc[RQ] = {};

    auto body = [&](const float4& kv, int g) {
        const float4 sc4 = *(const float4*)&scale[4 * g];    // wave-uniform
        #pragma unroll
        for (int r = 0; r < RQ; r++) {
            const float4 q4 = *(const float4*)&qrow[(size_t)r * UU + 4 * g];
            const float d0 = fmaf(q4.x, kv.x, 1.0f);
            const float d1 = fmaf(q4.y, kv.y, 1.0f);
            const float d2 = fmaf(q4.z, kv.z, 1.0f);
            const float d3 = fmaf(q4.w, kv.w, 1.0f);
            const float p01 = d0 * d1;
            const float p23 = d2 * d3;
            const float n01 = fmaf(sc4.x, d1, sc4.y * d0);
            const float n23 = fmaf(sc4.z, d3, sc4.w * d2);
            const float num = fmaf(n01, p23, n23 * p01);
            acc[r] = fmaf(num, frcp(p01 * p23), acc[r]);
        }
    };

    float4 c0 = kb4[0];
    float4 c1 = kb4[(size_t)TK];
    float4 c2 = kb4[(size_t)2 * TK];
    float4 c3 = kb4[(size_t)3 * TK];
    for (int g = 0; g < UU / 4; g += 4) {
        float4 n0v, n1v, n2v, n3v;
        if (g + 4 < UU / 4) {
            n0v = kb4[(size_t)(g + 4) * TK];
            n1v = kb4[(size_t)(g + 5) * TK];
            n2v = kb4[(size_t)(g + 6) * TK];
            n3v = kb4[(size_t)(g + 7) * TK];
        }
        body(c0, g); body(c1, g + 1); body(c2, g + 2); body(c3, g + 3);
        c0 = n0v; c1 = n1v; c2 = n2v; c3 = n3v;
    }
    #pragma unroll
    for (int r = 0; r < RQ; r++) acc[r] *= -2.0f;

    const int wave = t >> 6, lane = t & 63;
    float m[RQ], p[RQ];

    // row max over 512 threads
    #pragma unroll
    for (int r = 0; r < RQ; r++) {
        float v = acc[r];
        #pragma unroll
        for (int o = 32; o > 0; o >>= 1) v = fmaxf(v, __shfl_xor(v, o));
        if (lane == 0) redbuf[r][wave] = v;
    }
    __syncthreads();
    #pragma unroll
    for (int r = 0; r < RQ; r++) {
        float v = redbuf[r][0];
        #pragma unroll
        for (int w = 1; w < 8; w++) v = fmaxf(v, redbuf[r][w]);
        m[r] = v;
    }
    __syncthreads();

    // exp and row sum
    #pragma unroll
    for (int r = 0; r < RQ; r++) {
        p[r] = fexp2(L2E * (acc[r] - m[r]));
        float v = p[r];
        #pragma unroll
        for (int o = 32; o > 0; o >>= 1) v += __shfl_xor(v, o);
        if (lane == 0) redbuf[r][wave] = v;
    }
    __syncthreads();
    #pragma unroll
    for (int r = 0; r < RQ; r++) {
        float v = 0.0f;
        #pragma unroll
        for (int w = 0; w < 8; w++) v += redbuf[r][w];
        const float rinv = frcp(v);
        out[(size_t)(b * TQ + q0 + r) * TK + t] = p[r] * rinv;
    }
}

extern "C" void kernel_launch(void* const* d_in, const int* in_sizes, int n_in,
                              void* d_out, int out_size, void* d_ws, size_t ws_size,
                              hipStream_t stream) {
    const float* query = (const float*)d_in[0];
    const float* value = (const float*)d_in[1];
    const float* W1    = (const float*)d_in[2];
    const float* W2    = (const float*)d_in[3];
    const float* scale = (const float*)d_in[4];
    float* out = (float*)d_out;

    float* Eq = (float*)d_ws;                     // [BB*TQ, UU]      2 MB
    float* Ek = Eq + (size_t)BB * TQ * UU;        // [BB,UU/4,TK] f4  2 MB
    char* wbase = (char*)d_ws + 4 * 1048576;      // W planes: 4 x 256 KB
    u16* W1h = (u16*)(wbase);
    u16* W1l = (u16*)(wbase + 262144);
    u16* W2h = (u16*)(wbase + 524288);
    u16* W2l = (u16*)(wbase + 786432);
    (void)ws_size;  // needs 5 MB; harness provides 256 MB (verified R11/R12 profile)

    wsplit<<<256, 256, 0, stream>>>(W1, W2, W1h, W1l, W2h, W2l);
    proj3<<<dim3(64, 4, 2), 256, 0, stream>>>(query, value, W1h, W1l, W2h, W2l, Eq, Ek);
    attn_softmax<<<dim3(BB * TQ / RQ), 512, 0, stream>>>(Eq, Ek, scale, out);
}

// Round 3
// 105.020 us; speedup vs baseline: 1.0628x; 1.0134x over previous
//
#include <hip/hip_runtime.h>

#define BB 4
#define TQ 512
#define TK 512
#define DQ 512
#define UU 256
#define CSC 2.8853900817779268f   // 2*log2(e): Eq=2^(CSC*q), Ek=2^(CSC*k), e^{2y}=Eq*Ek
#define L2E 1.4426950408889634f
#define RQ 4
#define DSC 0x1.0p-14f            // Ek pre-scale c: d' = c*(1+Eq*Ek), folded into Ek store

typedef unsigned short u16;
typedef unsigned int u32;
typedef short bf16x8 __attribute__((ext_vector_type(8)));
typedef float f32x4 __attribute__((ext_vector_type(4)));

__device__ __forceinline__ float fexp2(float x) { return __builtin_amdgcn_exp2f(x); }
__device__ __forceinline__ float frcp(float x)  { return __builtin_amdgcn_rcpf(x); }
__device__ __forceinline__ u32 pkhi(u32 a, u32 b) { return (b & 0xffff0000u) | (a >> 16); }

// wsplit: transpose+split W1/W2 (fp32 [512k][256n]) -> Wh_t/Wl_t (u16 [256n][512k]).
__global__ __launch_bounds__(256) void wsplit(
    const float* __restrict__ W1, const float* __restrict__ W2,
    u16* __restrict__ W1h, u16* __restrict__ W1l,
    u16* __restrict__ W2h, u16* __restrict__ W2l)
{
    __shared__ float tile[32][33];
    const int blk = blockIdx.x, t = threadIdx.x;
    const float* W = (blk >> 7) ? W2 : W1;
    u16* oh = (blk >> 7) ? W2h : W1h;
    u16* ol = (blk >> 7) ? W2l : W1l;
    const int tl = blk & 127;
    const int k0 = (tl >> 3) * 32, n0 = (tl & 7) * 32;
    const int kl = t >> 5, nl = t & 31;
    #pragma unroll
    for (int r = 0; r < 4; r++)
        tile[kl + 8 * r][nl] = W[(size_t)(k0 + kl + 8 * r) * UU + n0 + nl];
    __syncthreads();
    const int nr = t >> 5, kc = t & 31;
    #pragma unroll
    for (int r = 0; r < 4; r++) {
        const float v = tile[kc][nr + 8 * r];
        const u32 x = __float_as_uint(v);
        const u16 h = (u16)(x >> 16);
        const u16 l = (u16)(__float_as_uint(v - __uint_as_float(x & 0xffff0000u)) >> 16);
        oh[(size_t)(n0 + nr + 8 * r) * DQ + k0 + kc] = h;
        ol[(size_t)(n0 + nr + 8 * r) * DQ + k0 + kc] = l;
    }
}

// proj3: C = A@W, split-bf16 MFMA (truncation split, 3 terms), exp2 epilogue.
// Tile 32m x 64n, K chunks of 32. A: global->split->LDS, double-buffered, 1 barrier/iter.
// W: pre-split planes, per-lane b128 global loads, register double-buffer issued AFTER
// the barrier so they drain at barrier(i+1). Grid (64,4,2) = 512 blocks, 4 waves each.
// z=0: Eq[m][u] = 2^(CSC*acc), row-major.
// z=1: Ek[b][u/4][j][4] = 2^(CSC*acc - 14)  (pre-scaled by 2^-14 for attn's 8-way
//      rcp batching; exponent shift is exact and free).
__global__ __launch_bounds__(256) void proj3(
    const float* __restrict__ Aq, const float* __restrict__ Av,
    const u16* __restrict__ W1h, const u16* __restrict__ W1l,
    const u16* __restrict__ W2h, const u16* __restrict__ W2l,
    float* __restrict__ Eq, float* __restrict__ Ek)
{
    __shared__ __align__(16) char raw[10240];   // 2 x 5120: Ah [32][40] + Al [32][40] u16
    float* fin = (float*)raw;                   // [32][68] f32, aliases after final barrier

    const int z = blockIdx.z;
    const float* A = z ? Av : Aq;
    const u16* Wh = z ? W2h : W1h;
    const u16* Wl = z ? W2l : W1l;

    const int t = threadIdx.x;
    const int m0 = blockIdx.x * 32, n0 = blockIdx.y * 64;
    const int wave = t >> 6, ln = t & 15, qd = (t & 63) >> 4;
    const int arow = t >> 3, ak4 = (t & 7) * 4;        // A staging: 4 fp32/thread
    const int ncol = n0 + wave * 16 + ln;
    const u16* whp = Wh + (size_t)ncol * DQ + qd * 8;
    const u16* wlp = Wl + (size_t)ncol * DQ + qd * 8;

    f32x4 acc[2] = {};

    float4 a4 = *(const float4*)&A[(size_t)(m0 + arow) * DQ + ak4];
    bf16x8 whc = *(const bf16x8*)&whp[0];
    bf16x8 wlc = *(const bf16x8*)&wlp[0];

    for (int i = 0; i < DQ / 32; i++) {
        char* buf = raw + (i & 1) * 5120;
        u16* Ah_s = (u16*)buf;
        u16* Al_s = (u16*)(buf + 2560);
        {   // A split -> bf16 hi/lo planes
            const float f[4] = {a4.x, a4.y, a4.z, a4.w};
            u32 x[4], lx[4];
            #pragma unroll
            for (int e = 0; e < 4; e++) {
                x[e]  = __float_as_uint(f[e]);
                lx[e] = __float_as_uint(f[e] - __uint_as_float(x[e] & 0xffff0000u));
            }
            uint2 hw, lw;
            hw.x = pkhi(x[0], x[1]);  hw.y = pkhi(x[2], x[3]);
            lw.x = pkhi(lx[0], lx[1]); lw.y = pkhi(lx[2], lx[3]);
            *(uint2*)&Ah_s[arow * 40 + ak4] = hw;
            *(uint2*)&Al_s[arow * 40 + ak4] = lw;
        }
        if (i + 1 < DQ / 32)
            a4 = *(const float4*)&A[(size_t)(m0 + arow) * DQ + (i + 1) * 32 + ak4];
        __syncthreads();

        bf16x8 whn, wln;
        if (i + 1 < DQ / 32) {  // W prefetch AFTER barrier -> drains at barrier(i+1)
            whn = *(const bf16x8*)&whp[(i + 1) * 32];
            wln = *(const bf16x8*)&wlp[(i + 1) * 32];
        }

        bf16x8 ah[2], al[2];
        #pragma unroll
        for (int ii = 0; ii < 2; ii++) {
            const int ar = (ii * 16 + ln) * 40 + qd * 8;
            ah[ii] = *(const bf16x8*)&Ah_s[ar];
            al[ii] = *(const bf16x8*)&Al_s[ar];
        }
        #pragma unroll
        for (int ii = 0; ii < 2; ii++) {
            acc[ii] = __builtin_amdgcn_mfma_f32_16x16x32_bf16(ah[ii], whc, acc[ii], 0, 0, 0);
            acc[ii] = __builtin_amdgcn_mfma_f32_16x16x32_bf16(ah[ii], wlc, acc[ii], 0, 0, 0);
            acc[ii] = __builtin_amdgcn_mfma_f32_16x16x32_bf16(al[ii], whc, acc[ii], 0, 0, 0);
        }
        whc = whn; wlc = wln;
    }

    if (z == 0) {
        #pragma unroll
        for (int ii = 0; ii < 2; ii++) {
            #pragma unroll
            for (int r = 0; r < 4; r++) {
                const int m = m0 + ii * 16 + qd * 4 + r;
                Eq[(size_t)m * UU + ncol] = fexp2(CSC * acc[ii][r]);
            }
        }
    } else {
        __syncthreads();
        #pragma unroll
        for (int ii = 0; ii < 2; ii++) {
            #pragma unroll
            for (int r = 0; r < 4; r++) {
                const int ml = ii * 16 + qd * 4 + r;
                const int nl = wave * 16 + ln;
                fin[ml * 68 + nl] = fexp2(fmaf(CSC, acc[ii][r], -14.0f));  // Ek * 2^-14
            }
        }
        __syncthreads();
        const int b = m0 >> 9, j0 = m0 & 511;
        #pragma unroll
        for (int p = 0; p < 2; p++) {
            const int idx = p * 256 + t;
            const int jl = idx & 31, u4 = idx >> 5;
            const float4 v = *(const float4*)&fin[jl * 68 + u4 * 4];
            ((float4*)Ek)[(size_t)(b * (UU / 4) + (n0 >> 2) + u4) * TK + j0 + jl] = v;
        }
    }
}

// attn+softmax: e^{2y} = Eq*Ek; shifted_score = -2*sum_u scale_u/(1+Eq*Ek).
// 8-way rcp batching (exact algebra), enabled by Ek pre-scale c=2^-14:
//   d'_i = fma(q_i, Ek'_i, c) = c*(1+Eq*Ek) ; binary tree of (N,P) merges
//   N' = Nl*Pr + Nr*Pl, P' = Pl*Pr ; sum = N/P ; homogeneous: sum' = 2^14 * sum,
//   corrected by final *(-2^-13). Range (5.9-sigma data max Eq*Ek ~ 2^27):
//   den in [2^-112, 2^107], num <= 2^99 -- no overflow/underflow, all normal.
// 30 VALU + 1 rcp per 8u per row = 68 issue cyc (was 2x(14+1) = 72). R2 validated
// the serial-issue model (rcp occupies issue slots, -10% predicted = -1.8 measured).
// 16-way impossible: product of 16 d's spans 2^416 >> fp32 range.
// NOTE (R1): f32x2/v_pk_fma_f32 NOT a win on gfx950 -- packed f32 is not double-rate.
// k prefetch: NAMED float4 regs, statically indexed (dynamically-indexed kbuf[4]
// got LDS-promoted: 33KB alloca + 1.9e7 bank conflicts -- never index these).
__global__ __launch_bounds__(512) void attn_softmax(
    const float* __restrict__ Eq,    // [BB, TQ, UU]
    const float* __restrict__ Ek,    // [BB, UU/4, TK] of float4 (interleaved u, *2^-14)
    const float* __restrict__ scale, // [UU]
    float* __restrict__ out)         // [BB, TQ, TK]
{
    __shared__ float redbuf[RQ][8];
    const int t  = threadIdx.x;
    const int b  = blockIdx.x >> 7;            // 128 blocks per b
    const int q0 = (blockIdx.x & 127) * RQ;
    const float*  qrow = Eq + (size_t)(b * TQ + q0) * UU;   // wave-uniform
    const float4* kb4  = (const float4*)Ek + (size_t)b * (UU / 4) * TK + t;

    float acc[RQ] = {};

    // body8: u = 4*g4 .. 4*g4+7 (two float4 k-vectors)
    auto body8 = [&](const float4& kva, const float4& kvb, int g4) {
        const float4 sa = *(const float4*)&scale[4 * g4];        // wave-uniform
        const float4 sb = *(const float4*)&scale[4 * g4 + 4];
        #pragma unroll
        for (int r = 0; r < RQ; r++) {
            const float4 qa = *(const float4*)&qrow[(size_t)r * UU + 4 * g4];
            const float4 qb = *(const float4*)&qrow[(size_t)r * UU + 4 * g4 + 4];
            const float d0 = fmaf(qa.x, kva.x, DSC);
            const float d1 = fmaf(qa.y, kva.y, DSC);
            const float d2 = fmaf(qa.z, kva.z, DSC);
            const float d3 = fmaf(qa.w, kva.w, DSC);
            const float d4 = fmaf(qb.x, kvb.x, DSC);
            const float d5 = fmaf(qb.y, kvb.y, DSC);
            const float d6 = fmaf(qb.z, kvb.z, DSC);
            const float d7 = fmaf(qb.w, kvb.w, DSC);
            const float p01 = d0 * d1, p23 = d2 * d3;
            const float p45 = d4 * d5, p67 = d6 * d7;
            const float n01 = fmaf(sa.x, d1, sa.y * d0);
            const float n23 = fmaf(sa.z, d3, sa.w * d2);
            const float n45 = fmaf(sb.x, d5, sb.y * d4);
            const float n67 = fmaf(sb.z, d7, sb.w * d6);
            const float P03 = p01 * p23, P47 = p45 * p67;
            const float N03 = fmaf(n01, p23, n23 * p01);
            const float N47 = fmaf(n45, p67, n67 * p45);
            const float num = fmaf(N03, P47, N47 * P03);
            acc[r] = fmaf(num, frcp(P03 * P47), acc[r]);
        }
    };

    float4 c0 = kb4[0];
    float4 c1 = kb4[(size_t)TK];
    float4 c2 = kb4[(size_t)2 * TK];
    float4 c3 = kb4[(size_t)3 * TK];
    for (int g = 0; g < UU / 4; g += 4) {
        float4 n0v, n1v, n2v, n3v;
        if (g + 4 < UU / 4) {
            n0v = kb4[(size_t)(g + 4) * TK];
            n1v = kb4[(size_t)(g + 5) * TK];
            n2v = kb4[(size_t)(g + 6) * TK];
            n3v = kb4[(size_t)(g + 7) * TK];
        }
        body8(c0, c1, g);
        body8(c2, c3, g + 2);
        c0 = n0v; c1 = n1v; c2 = n2v; c3 = n3v;
    }
    #pragma unroll
    for (int r = 0; r < RQ; r++) acc[r] *= -0x1.0p-13f;   // -2 * 2^-14 homogeneity fix

    const int wave = t >> 6, lane = t & 63;
    float m[RQ], p[RQ];

    // row max over 512 threads
    #pragma unroll
    for (int r = 0; r < RQ; r++) {
        float v = acc[r];
        #pragma unroll
        for (int o = 32; o > 0; o >>= 1) v = fmaxf(v, __shfl_xor(v, o));
        if (lane == 0) redbuf[r][wave] = v;
    }
    __syncthreads();
    #pragma unroll
    for (int r = 0; r < RQ; r++) {
        float v = redbuf[r][0];
        #pragma unroll
        for (int w = 1; w < 8; w++) v = fmaxf(v, redbuf[r][w]);
        m[r] = v;
    }
    __syncthreads();

    // exp and row sum
    #pragma unroll
    for (int r = 0; r < RQ; r++) {
        p[r] = fexp2(L2E * (acc[r] - m[r]));
        float v = p[r];
        #pragma unroll
        for (int o = 32; o > 0; o >>= 1) v += __shfl_xor(v, o);
        if (lane == 0) redbuf[r][wave] = v;
    }
    __syncthreads();
    #pragma unroll
    for (int r = 0; r < RQ; r++) {
        float v = 0.0f;
        #pragma unroll
        for (int w = 0; w < 8; w++) v += redbuf[r][w];
        const float rinv = frcp(v);
        out[(size_t)(b * TQ + q0 + r) * TK + t] = p[r] * rinv;
    }
}

extern "C" void kernel_launch(void* const* d_in, const int* in_sizes, int n_in,
                              void* d_out, int out_size, void* d_ws, size_t ws_size,
                              hipStream_t stream) {
    const float* query = (const float*)d_in[0];
    const float* value = (const float*)d_in[1];
    const float* W1    = (const float*)d_in[2];
    const float* W2    = (const float*)d_in[3];
    const float* scale = (const float*)d_in[4];
    float* out = (float*)d_out;

    float* Eq = (float*)d_ws;                     // [BB*TQ, UU]      2 MB
    float* Ek = Eq + (size_t)BB * TQ * UU;        // [BB,UU/4,TK] f4  2 MB
    char* wbase = (char*)d_ws + 4 * 1048576;      // W planes: 4 x 256 KB
    u16* W1h = (u16*)(wbase);
    u16* W1l = (u16*)(wbase + 262144);
    u16* W2h = (u16*)(wbase + 524288);
    u16* W2l = (u16*)(wbase + 786432);
    (void)ws_size;  // needs 5 MB; harness provides 256 MB (verified R11/R12 profile)

    wsplit<<<256, 256, 0, stream>>>(W1, W2, W1h, W1l, W2h, W2l);
    proj3<<<dim3(64, 4, 2), 256, 0, stream>>>(query, value, W1h, W1l, W2h, W2l, Eq, Ek);
    attn_softmax<<<dim3(BB * TQ / RQ), 512, 0, stream>>>(Eq, Ek, scale, out);
}